// Round 18
// baseline (116.080 us; speedup 1.0000x reference)
//
#include <hip/hip_runtime.h>
#include <math.h>

#define DIM 394
#define KP  416      // padded K = 13*32
#define NT  13       // K-steps
#define NP  448      // padded N = 28*16
#define BN_EPS 1e-5f
#define MAXD 32      // payload slots/node = one 128B L2 line
#define TST 452      // transpose-tile LDS row stride (words)

typedef __bf16 bf16x8 __attribute__((ext_vector_type(8)));
typedef __bf16 bf16x4 __attribute__((ext_vector_type(4)));
typedef float  f32x4  __attribute__((ext_vector_type(4)));

// wave-uniform layout probe: int64 edge_index has all odd 32-bit words == 0
__device__ inline bool edges_are_int32(const int* ei) {
    int l = threadIdx.x & 63;
    unsigned long long b = __ballot(ei[2 * l + 1] != 0);
    return b != 0ULL;
}

// ---------------------------------------------------------------------------
// ws layout: degc[n] u32 | yover[2n] f32 | ocnt[4] u32 | xs2[n] float2 |
//            olist[e] uint2 | (align 256) payload[n*MAXD] u32 | Bp | Pk | Ok
// ---------------------------------------------------------------------------

__global__ void prep_kernel(const float* __restrict__ Wg, const float* __restrict__ bg,
                            const float* __restrict__ gamma, const float* __restrict__ beta,
                            const float* __restrict__ mean, const float* __restrict__ var,
                            const float* __restrict__ fcw,
                            uint4* __restrict__ zbase, float4* __restrict__ Pk,
                            float* __restrict__ Ok, bf16x8* __restrict__ Bp,
                            int z4, int zb) {
    int b = blockIdx.x, t = threadIdx.x;
    if (b < zb) {                        // zero degc + yover + ocnt
        int i = b * 256 + t;
        if (i < z4) zbase[i] = make_uint4(0u, 0u, 0u, 0u);
    } else if (b < zb + 2) {             // Pk/Ok: per-k GCN+BN constants
        int k = (b - zb) * 256 + t;
        if (k < KP) {
            float4 p = make_float4(0.f, 0.f, 0.f, 0.f);
            float o = 0.f;
            if (k < DIM) {
                p.x = Wg[2 * k];
                p.y = Wg[2 * k + 1];
                p.z = bg[k];
                float sc = gamma[k] * rsqrtf(var[k] + BN_EPS);
                p.w = sc;
                o = beta[k] - sc * mean[k];
            }
            Pk[k] = p;
            Ok[k] = o;
        }
    } else {                             // B = fc_w^T packed bf16 fragments
        int idx = (b - zb - 2) * 256 + t;
        if (idx < NT * 4 * NP) {
            int col = idx % NP;
            int r   = idx / NP;          // ks*4 + kc
            int k0  = r * 8;
            bf16x8 v;
            #pragma unroll
            for (int q = 0; q < 8; ++q) {
                int k = k0 + q;
                float f = (col < DIM && k < DIM) ? fcw[col * DIM + k] : 0.0f;
                v[q] = (__bf16)f;
            }
            Bp[idx] = v;
        }
    }
}

// place: ticket-CSR, 32 edges/thread for atomic-latency MLP. 1 atomic/edge.
__global__ void place_kernel(const int* __restrict__ ei,
                             unsigned* __restrict__ degc,
                             unsigned* __restrict__ payload,
                             unsigned* __restrict__ ocnt,
                             uint2* __restrict__ olist, int e) {
    bool is32 = edges_are_int32(ei);
    int i0 = (blockIdx.x * blockDim.x + threadIdx.x) * 32;
    if (i0 >= e) return;
    int s[32], d[32];
    int cnt = 32;
    if (i0 + 32 <= e && (e & 31) == 0) {
        if (is32) {
            #pragma unroll
            for (int v = 0; v < 8; ++v) {
                int4 a = *reinterpret_cast<const int4*>(&ei[i0 + 4 * v]);
                int4 c = *reinterpret_cast<const int4*>(&ei[e + i0 + 4 * v]);
                s[4*v] = a.x; s[4*v+1] = a.y; s[4*v+2] = a.z; s[4*v+3] = a.w;
                d[4*v] = c.x; d[4*v+1] = c.y; d[4*v+2] = c.z; d[4*v+3] = c.w;
            }
        } else {
            #pragma unroll
            for (int v = 0; v < 16; ++v) {
                int4 a = *reinterpret_cast<const int4*>(&ei[2 * i0 + 4 * v]);
                int4 c = *reinterpret_cast<const int4*>(&ei[2 * (e + i0) + 4 * v]);
                s[2*v] = a.x; s[2*v+1] = a.z;
                d[2*v] = c.x; d[2*v+1] = c.z;
            }
        }
    } else {
        cnt = e - i0 < 32 ? e - i0 : 32;
        for (int j = 0; j < cnt; ++j) {
            s[j] = is32 ? ei[i0 + j]     : ei[2 * (i0 + j)];
            d[j] = is32 ? ei[e + i0 + j] : ei[2 * (e + i0 + j)];
        }
    }
    #pragma unroll
    for (int j = 0; j < 32; ++j) {
        if (j >= cnt) break;
        unsigned tk = atomicAdd(&degc[d[j]], 1u);
        if (tk < MAXD) {
            payload[(size_t)d[j] * MAXD + tk] = (unsigned)s[j];
        } else {
            unsigned o = atomicAdd(ocnt, 1u);
            olist[o] = make_uint2((unsigned)s[j], (unsigned)d[j]);
        }
    }
}

// xs2[i] = dinv_i * x[i]  (coalesced) + drain overflow edges into yover
__global__ void xs_cleanup_kernel(const float2* __restrict__ x2,
                                  const unsigned* __restrict__ degc,
                                  float2* __restrict__ xs2,
                                  const uint2* __restrict__ olist,
                                  const unsigned* __restrict__ ocnt,
                                  float* __restrict__ yover, int n, int nb0) {
    int b = blockIdx.x;
    if (b < nb0) {
        int i = b * 256 + threadIdx.x;
        if (i < n) {
            float di = rsqrtf(1.0f + (float)degc[i]);
            float2 xv = x2[i];
            xs2[i] = make_float2(di * xv.x, di * xv.y);
        }
    } else {
        unsigned cnt = *ocnt;
        unsigned t = (b - nb0) * 256 + threadIdx.x;
        for (unsigned i = t; i < cnt; i += 512) {
            uint2 sd = olist[i];
            float ds = rsqrtf(1.0f + (float)degc[sd.x]);
            float2 xv = x2[sd.x];
            atomicAdd(&yover[2 * sd.y],     ds * xv.x);
            atomicAdd(&yover[2 * sd.y + 1], ds * xv.y);
        }
    }
}

// ---------------------------------------------------------------------------
// Fused gemm, BM=32 / acc[2][7] / single-buffered B (r17 version, 114.8us).
// ---------------------------------------------------------------------------
__global__ __launch_bounds__(256, 4)
void gemm_fused(const float2* __restrict__ xs2, const unsigned* __restrict__ degc,
                const unsigned* __restrict__ payload, const float* __restrict__ yover,
                const float4* __restrict__ PkG, const float* __restrict__ OkG,
                const bf16x8* __restrict__ Bp, const float* __restrict__ fcb,
                float* __restrict__ outp, float* __restrict__ z, int n) {
    __shared__ alignas(16) char smem[16 * TST * 4 + 64];
    bf16x4* As4  = (bf16x4*)smem;
    float2* red  = (float2*)(smem + 4096);
    float4* PkL  = (float4*)(smem + 6144);
    float*  OkL  = (float*)(smem + 12800);
    float*  T    = (float*)smem;
    float*  lsebuf = (float*)(smem + 16 * TST * 4);

    int tid = threadIdx.x;
    int wv  = tid >> 6;              // wave id == col quarter
    int cg_ = tid & 15;
    int kg  = (tid & 63) >> 4;
    int row0 = blockIdx.x * 32;

    int srow  = tid & 31;
    int skc   = (tid >> 5) & 3;
    int shalf = tid >> 7;
    int p8    = tid >> 5;            // 8 gather parts per row
    int gi = row0 + srow;

    for (int i = tid; i < KP; i += 256) {
        PkL[i] = PkG[i];
        OkL[i] = OkG[i];
    }

    float y0 = 0.f, y1 = 0.f;
    {
        float2 psum = make_float2(0.f, 0.f);
        float dinv_i = 0.f;
        float2 xsg = make_float2(0.f, 0.f);
        if (gi < n) {
            unsigned dg = degc[gi];
            dinv_i = rsqrtf(1.0f + (float)dg);
            xsg = xs2[gi];
            unsigned m = dg < MAXD ? dg : MAXD;
            const unsigned* pl = payload + (size_t)gi * MAXD;
            for (unsigned t = p8; t < m; t += 8) {
                float2 xv = xs2[pl[t]];
                psum.x += xv.x;
                psum.y += xv.y;
            }
            if (p8 == 0) {
                psum.x += yover[2 * gi];
                psum.y += yover[2 * gi + 1];
            }
        }
        red[srow * 8 + p8] = psum;
        __syncthreads();
        if (gi < n) {
            float sx = 0.f, sy = 0.f;
            #pragma unroll
            for (int p = 0; p < 8; ++p) {
                sx += red[srow * 8 + p].x;
                sy += red[srow * 8 + p].y;
            }
            y0 = dinv_i * (sx + xsg.x);
            y1 = dinv_i * (sy + xsg.y);
        }
    }

    f32x4 acc[2][7];
    #pragma unroll
    for (int a = 0; a < 2; ++a)
        #pragma unroll
        for (int b = 0; b < 7; ++b)
            acc[a][b] = (f32x4){0.f, 0.f, 0.f, 0.f};

    auto stageA = [&](int ks, int buf) {
        int kb = ks * 32 + skc * 8 + shalf * 4;
        bf16x4 hv;
        #pragma unroll
        for (int q = 0; q < 4; ++q) {
            float4 p = PkL[kb + q];
            float t = fmaf(y0, p.x, fmaf(y1, p.y, p.z));
            t = fmaxf(t, 0.f);
            hv[q] = (__bf16)fmaf(p.w, t, OkL[kb + q]);
        }
        As4[buf * 256 + (skc * 32 + srow) * 2 + shalf] = hv;
    };

    const bf16x8* bptr = Bp + (kg * 448 + wv * 112 + cg_);

    stageA(0, 0);
    __syncthreads();

    int buf = 0;
    for (int ks = 0; ks < NT; ++ks) {
        bf16x8 Bcur[7];
        const bf16x8* bk = bptr + (size_t)ks * 1792;
        #pragma unroll
        for (int c = 0; c < 7; ++c) Bcur[c] = bk[c * 16];
        if (ks < NT - 1) stageA(ks + 1, buf ^ 1);
        const bf16x8* As8 = (const bf16x8*)As4 + buf * 128;
        bf16x8 af[2];
        #pragma unroll
        for (int rt = 0; rt < 2; ++rt)
            af[rt] = As8[kg * 32 + rt * 16 + cg_];
        #pragma unroll
        for (int ct = 0; ct < 7; ++ct)
            #pragma unroll
            for (int rt = 0; rt < 2; ++rt)
                acc[rt][ct] = __builtin_amdgcn_mfma_f32_16x16x32_bf16(
                                  af[rt], Bcur[ct], acc[rt][ct], 0, 0, 0);
        __syncthreads();
        buf ^= 1;
    }

    float* redm = (float*)smem;
    float* reds = redm + 128;

    int colb = wv * 112;
    float bias[7];
    bool  cv[7];
    #pragma unroll
    for (int ct = 0; ct < 7; ++ct) {
        int c = colb + ct * 16 + cg_;
        cv[ct] = (c < DIM);
        bias[ct] = cv[ct] ? fcb[c] : 0.f;
    }
    #pragma unroll
    for (int rt = 0; rt < 2; ++rt)
        #pragma unroll
        for (int ct = 0; ct < 7; ++ct)
            acc[rt][ct] = acc[rt][ct] + bias[ct];

    f32x4 mx[2];
    #pragma unroll
    for (int rt = 0; rt < 2; ++rt) {
        f32x4 m = (f32x4){-1e30f, -1e30f, -1e30f, -1e30f};
        #pragma unroll
        for (int ct = 0; ct < 7; ++ct) {
            if (!cv[ct]) continue;
            #pragma unroll
            for (int j = 0; j < 4; ++j) m[j] = fmaxf(m[j], acc[rt][ct][j]);
        }
        #pragma unroll
        for (int msk = 1; msk < 16; msk <<= 1)
            #pragma unroll
            for (int j = 0; j < 4; ++j)
                m[j] = fmaxf(m[j], __shfl_xor(m[j], msk));
        mx[rt] = m;
    }
    __syncthreads();
    if (cg_ == 0) {
        #pragma unroll
        for (int rt = 0; rt < 2; ++rt)
            #pragma unroll
            for (int j = 0; j < 4; ++j)
                redm[(rt * 16 + kg * 4 + j) * 4 + wv] = mx[rt][j];
    }
    __syncthreads();
    f32x4 gm[2];
    #pragma unroll
    for (int rt = 0; rt < 2; ++rt)
        #pragma unroll
        for (int j = 0; j < 4; ++j) {
            int r = (rt * 16 + kg * 4 + j) * 4;
            gm[rt][j] = fmaxf(fmaxf(redm[r], redm[r + 1]),
                              fmaxf(redm[r + 2], redm[r + 3]));
        }

    f32x4 sm[2];
    #pragma unroll
    for (int rt = 0; rt < 2; ++rt) {
        f32x4 s = (f32x4){0.f, 0.f, 0.f, 0.f};
        #pragma unroll
        for (int ct = 0; ct < 7; ++ct) {
            if (!cv[ct]) continue;
            #pragma unroll
            for (int j = 0; j < 4; ++j)
                s[j] += __expf(acc[rt][ct][j] - gm[rt][j]);
        }
        #pragma unroll
        for (int msk = 1; msk < 16; msk <<= 1)
            #pragma unroll
            for (int j = 0; j < 4; ++j)
                s[j] += __shfl_xor(s[j], msk);
        sm[rt] = s;
    }
    if (cg_ == 0) {
        #pragma unroll
        for (int rt = 0; rt < 2; ++rt)
            #pragma unroll
            for (int j = 0; j < 4; ++j)
                reds[(rt * 16 + kg * 4 + j) * 4 + wv] = sm[rt][j];
    }
    __syncthreads();
    f32x4 lse[2];
    #pragma unroll
    for (int rt = 0; rt < 2; ++rt)
        #pragma unroll
        for (int j = 0; j < 4; ++j) {
            int r = (rt * 16 + kg * 4 + j) * 4;
            float t = reds[r] + reds[r + 1] + reds[r + 2] + reds[r + 3];
            lse[rt][j] = gm[rt][j] + __logf(t);
        }
    __syncthreads();

    #pragma unroll
    for (int rt = 0; rt < 2; ++rt) {
        #pragma unroll
        for (int ct = 0; ct < 7; ++ct) {
            int c = colb + ct * 16 + cg_;
            #pragma unroll
            for (int j = 0; j < 4; ++j)
                T[(kg * 4 + j) * TST + c] = acc[rt][ct][j];
        }
        if (wv == 0 && cg_ == 0) {
            #pragma unroll
            for (int j = 0; j < 4; ++j)
                lsebuf[kg * 4 + j] = lse[rt][j];
        }
        __syncthreads();
        #pragma unroll
        for (int q = 0; q < 7; ++q) {
            int idx = tid + q * 256;
            int row = idx / 112;
            int c4  = idx - row * 112;
            int grow2 = row0 + rt * 16 + row;
            if (grow2 < n && c4 <= 98) {
                float4 v = *reinterpret_cast<const float4*>(&T[row * TST + c4 * 4]);
                float L = lsebuf[row];
                size_t base = (size_t)grow2 * DIM + c4 * 4;
                if (c4 <= 97) {
                    *reinterpret_cast<float2*>(&z[base])        = make_float2(v.x, v.y);
                    *reinterpret_cast<float2*>(&z[base + 2])    = make_float2(v.z, v.w);
                    *reinterpret_cast<float2*>(&outp[base])     = make_float2(v.x - L, v.y - L);
                    *reinterpret_cast<float2*>(&outp[base + 2]) = make_float2(v.z - L, v.w - L);
                } else {
                    *reinterpret_cast<float2*>(&z[base])    = make_float2(v.x, v.y);
                    *reinterpret_cast<float2*>(&outp[base]) = make_float2(v.x - L, v.y - L);
                }
            }
        }
        __syncthreads();
    }
}

// ---------------------------------------------------------------------------
extern "C" void kernel_launch(void* const* d_in, const int* in_sizes, int n_in,
                              void* d_out, int out_size, void* d_ws, size_t ws_size,
                              hipStream_t stream) {
    int n = in_sizes[0] / 2;       // 50000 nodes
    int e = in_sizes[1] / 2;       // 800000 edges

    const float2* x2   = (const float2*)d_in[0];
    const int*   ei    = (const int*)d_in[1];
    const float* Wg    = (const float*)d_in[2];
    const float* bg    = (const float*)d_in[3];
    const float* gamma = (const float*)d_in[4];
    const float* beta  = (const float*)d_in[5];
    const float* mean  = (const float*)d_in[6];
    const float* var   = (const float*)d_in[7];
    const float* fcw   = (const float*)d_in[8];
    const float* fcb   = (const float*)d_in[9];

    float* out = (float*)d_out;
    float* z   = out + (size_t)n * DIM;

    char* wsb = (char*)d_ws;
    unsigned* degc  = (unsigned*)wsb;
    float*    yover = (float*)(degc + n);
    unsigned* ocnt  = (unsigned*)(yover + 2 * (size_t)n);
    float2*   xs2   = (float2*)(ocnt + 4);
    uint2*    olist = (uint2*)(xs2 + n);
    size_t off = (size_t)(5 * n + 4) * 4 + (size_t)e * 8;
    off = (off + 255) & ~(size_t)255;
    unsigned* payload = (unsigned*)(wsb + off);
    off += (size_t)n * MAXD * 4;
    off = (off + 255) & ~(size_t)255;
    bf16x8* Bp = (bf16x8*)(wsb + off);
    off += (size_t)NT * 4 * NP * 16;
    float4* Pk = (float4*)(wsb + off);
    off += (size_t)KP * 16;
    float* Ok  = (float*)(wsb + off);

    int zwords = 3 * n + 4;
    int z4 = (zwords + 3) / 4;
    int zb = (z4 + 255) / 256;
    int prep_blocks = zb + 2 + (NT * 4 * NP + 255) / 256;
    int eb32 = (e / 32 + 255) / 256 + 1;
    int nb0 = (n + 255) / 256;

    prep_kernel<<<prep_blocks, 256, 0, stream>>>(Wg, bg, gamma, beta, mean, var,
                                                 fcw, (uint4*)degc, Pk, Ok, Bp,
                                                 z4, zb);
    place_kernel<<<eb32, 256, 0, stream>>>(ei, degc, payload, ocnt, olist, e);
    xs_cleanup_kernel<<<nb0 + 2, 256, 0, stream>>>(x2, degc, xs2, olist, ocnt,
                                                   yover, n, nb0);

    int gm = (n + 31) / 32;
    gemm_fused<<<gm, 256, 0, stream>>>(xs2, degc, payload, yover,
                                       Pk, Ok, Bp, fcb, out, z, n);
}

// Round 19
// 114.675 us; speedup vs baseline: 1.0123x; 1.0123x over previous
//
#include <hip/hip_runtime.h>
#include <math.h>

#define DIM 394
#define KP  416      // padded K = 13*32
#define NT  13       // K-steps
#define NP  448      // padded N = 28*16
#define BN_EPS 1e-5f
#define MAXD 32      // payload slots/node = one 128B L2 line
#define TST 452      // transpose-tile LDS row stride (words)

typedef __bf16 bf16x8 __attribute__((ext_vector_type(8)));
typedef __bf16 bf16x4 __attribute__((ext_vector_type(4)));
typedef float  f32x4  __attribute__((ext_vector_type(4)));

// wave-uniform layout probe: int64 edge_index has all odd 32-bit words == 0
__device__ inline bool edges_are_int32(const int* ei) {
    int l = threadIdx.x & 63;
    unsigned long long b = __ballot(ei[2 * l + 1] != 0);
    return b != 0ULL;
}

// ---------------------------------------------------------------------------
// ws layout: degc[n] u32 | yover[2n] f32 | ocnt[4] u32 | xs2[n] float2 |
//            olist[e] uint2 | (align 256) payload[n*MAXD] u32 | Bp | Pk | Ok
// Best-measured configuration (r17): place 16 edges/thread, BM=32 gemm.
// ---------------------------------------------------------------------------

__global__ void prep_kernel(const float* __restrict__ Wg, const float* __restrict__ bg,
                            const float* __restrict__ gamma, const float* __restrict__ beta,
                            const float* __restrict__ mean, const float* __restrict__ var,
                            const float* __restrict__ fcw,
                            uint4* __restrict__ zbase, float4* __restrict__ Pk,
                            float* __restrict__ Ok, bf16x8* __restrict__ Bp,
                            int z4, int zb) {
    int b = blockIdx.x, t = threadIdx.x;
    if (b < zb) {                        // zero degc + yover + ocnt
        int i = b * 256 + t;
        if (i < z4) zbase[i] = make_uint4(0u, 0u, 0u, 0u);
    } else if (b < zb + 2) {             // Pk/Ok: per-k GCN+BN constants
        int k = (b - zb) * 256 + t;
        if (k < KP) {
            float4 p = make_float4(0.f, 0.f, 0.f, 0.f);
            float o = 0.f;
            if (k < DIM) {
                p.x = Wg[2 * k];
                p.y = Wg[2 * k + 1];
                p.z = bg[k];
                float sc = gamma[k] * rsqrtf(var[k] + BN_EPS);
                p.w = sc;
                o = beta[k] - sc * mean[k];
            }
            Pk[k] = p;
            Ok[k] = o;
        }
    } else {                             // B = fc_w^T packed bf16 fragments
        int idx = (b - zb - 2) * 256 + t;
        if (idx < NT * 4 * NP) {
            int col = idx % NP;
            int r   = idx / NP;          // ks*4 + kc
            int k0  = r * 8;
            bf16x8 v;
            #pragma unroll
            for (int q = 0; q < 8; ++q) {
                int k = k0 + q;
                float f = (col < DIM && k < DIM) ? fcw[col * DIM + k] : 0.0f;
                v[q] = (__bf16)f;
            }
            Bp[idx] = v;
        }
    }
}

// place: ticket-CSR, 16 edges/thread (measured atomic-MLP optimum).
__global__ void place_kernel(const int* __restrict__ ei,
                             unsigned* __restrict__ degc,
                             unsigned* __restrict__ payload,
                             unsigned* __restrict__ ocnt,
                             uint2* __restrict__ olist, int e) {
    bool is32 = edges_are_int32(ei);
    int i0 = (blockIdx.x * blockDim.x + threadIdx.x) * 16;
    if (i0 >= e) return;
    int s[16], d[16];
    int cnt = 16;
    if (i0 + 16 <= e && (e & 15) == 0) {
        if (is32) {
            #pragma unroll
            for (int v = 0; v < 4; ++v) {
                int4 a = *reinterpret_cast<const int4*>(&ei[i0 + 4 * v]);
                int4 c = *reinterpret_cast<const int4*>(&ei[e + i0 + 4 * v]);
                s[4*v] = a.x; s[4*v+1] = a.y; s[4*v+2] = a.z; s[4*v+3] = a.w;
                d[4*v] = c.x; d[4*v+1] = c.y; d[4*v+2] = c.z; d[4*v+3] = c.w;
            }
        } else {
            #pragma unroll
            for (int v = 0; v < 8; ++v) {
                int4 a = *reinterpret_cast<const int4*>(&ei[2 * i0 + 4 * v]);
                int4 c = *reinterpret_cast<const int4*>(&ei[2 * (e + i0) + 4 * v]);
                s[2*v] = a.x; s[2*v+1] = a.z;
                d[2*v] = c.x; d[2*v+1] = c.z;
            }
        }
    } else {
        cnt = e - i0 < 16 ? e - i0 : 16;
        for (int j = 0; j < cnt; ++j) {
            s[j] = is32 ? ei[i0 + j]     : ei[2 * (i0 + j)];
            d[j] = is32 ? ei[e + i0 + j] : ei[2 * (e + i0 + j)];
        }
    }
    #pragma unroll
    for (int j = 0; j < 16; ++j) {
        if (j >= cnt) break;
        unsigned tk = atomicAdd(&degc[d[j]], 1u);
        if (tk < MAXD) {
            payload[(size_t)d[j] * MAXD + tk] = (unsigned)s[j];
        } else {
            unsigned o = atomicAdd(ocnt, 1u);
            olist[o] = make_uint2((unsigned)s[j], (unsigned)d[j]);
        }
    }
}

// xs2[i] = dinv_i * x[i]  (coalesced) + drain overflow edges into yover
__global__ void xs_cleanup_kernel(const float2* __restrict__ x2,
                                  const unsigned* __restrict__ degc,
                                  float2* __restrict__ xs2,
                                  const uint2* __restrict__ olist,
                                  const unsigned* __restrict__ ocnt,
                                  float* __restrict__ yover, int n, int nb0) {
    int b = blockIdx.x;
    if (b < nb0) {
        int i = b * 256 + threadIdx.x;
        if (i < n) {
            float di = rsqrtf(1.0f + (float)degc[i]);
            float2 xv = x2[i];
            xs2[i] = make_float2(di * xv.x, di * xv.y);
        }
    } else {
        unsigned cnt = *ocnt;
        unsigned t = (b - nb0) * 256 + threadIdx.x;
        for (unsigned i = t; i < cnt; i += 512) {
            uint2 sd = olist[i];
            float ds = rsqrtf(1.0f + (float)degc[sd.x]);
            float2 xv = x2[sd.x];
            atomicAdd(&yover[2 * sd.y],     ds * xv.x);
            atomicAdd(&yover[2 * sd.y + 1], ds * xv.y);
        }
    }
}

// ---------------------------------------------------------------------------
// Fused gemm, BM=32 / acc[2][7] / single-buffered B (r17 version, 114.8us).
// ---------------------------------------------------------------------------
__global__ __launch_bounds__(256, 4)
void gemm_fused(const float2* __restrict__ xs2, const unsigned* __restrict__ degc,
                const unsigned* __restrict__ payload, const float* __restrict__ yover,
                const float4* __restrict__ PkG, const float* __restrict__ OkG,
                const bf16x8* __restrict__ Bp, const float* __restrict__ fcb,
                float* __restrict__ outp, float* __restrict__ z, int n) {
    __shared__ alignas(16) char smem[16 * TST * 4 + 64];
    bf16x4* As4  = (bf16x4*)smem;
    float2* red  = (float2*)(smem + 4096);
    float4* PkL  = (float4*)(smem + 6144);
    float*  OkL  = (float*)(smem + 12800);
    float*  T    = (float*)smem;
    float*  lsebuf = (float*)(smem + 16 * TST * 4);

    int tid = threadIdx.x;
    int wv  = tid >> 6;              // wave id == col quarter
    int cg_ = tid & 15;
    int kg  = (tid & 63) >> 4;
    int row0 = blockIdx.x * 32;

    int srow  = tid & 31;
    int skc   = (tid >> 5) & 3;
    int shalf = tid >> 7;
    int p8    = tid >> 5;            // 8 gather parts per row
    int gi = row0 + srow;

    for (int i = tid; i < KP; i += 256) {
        PkL[i] = PkG[i];
        OkL[i] = OkG[i];
    }

    float y0 = 0.f, y1 = 0.f;
    {
        float2 psum = make_float2(0.f, 0.f);
        float dinv_i = 0.f;
        float2 xsg = make_float2(0.f, 0.f);
        if (gi < n) {
            unsigned dg = degc[gi];
            dinv_i = rsqrtf(1.0f + (float)dg);
            xsg = xs2[gi];
            unsigned m = dg < MAXD ? dg : MAXD;
            const unsigned* pl = payload + (size_t)gi * MAXD;
            for (unsigned t = p8; t < m; t += 8) {
                float2 xv = xs2[pl[t]];
                psum.x += xv.x;
                psum.y += xv.y;
            }
            if (p8 == 0) {
                psum.x += yover[2 * gi];
                psum.y += yover[2 * gi + 1];
            }
        }
        red[srow * 8 + p8] = psum;
        __syncthreads();
        if (gi < n) {
            float sx = 0.f, sy = 0.f;
            #pragma unroll
            for (int p = 0; p < 8; ++p) {
                sx += red[srow * 8 + p].x;
                sy += red[srow * 8 + p].y;
            }
            y0 = dinv_i * (sx + xsg.x);
            y1 = dinv_i * (sy + xsg.y);
        }
    }

    f32x4 acc[2][7];
    #pragma unroll
    for (int a = 0; a < 2; ++a)
        #pragma unroll
        for (int b = 0; b < 7; ++b)
            acc[a][b] = (f32x4){0.f, 0.f, 0.f, 0.f};

    auto stageA = [&](int ks, int buf) {
        int kb = ks * 32 + skc * 8 + shalf * 4;
        bf16x4 hv;
        #pragma unroll
        for (int q = 0; q < 4; ++q) {
            float4 p = PkL[kb + q];
            float t = fmaf(y0, p.x, fmaf(y1, p.y, p.z));
            t = fmaxf(t, 0.f);
            hv[q] = (__bf16)fmaf(p.w, t, OkL[kb + q]);
        }
        As4[buf * 256 + (skc * 32 + srow) * 2 + shalf] = hv;
    };

    const bf16x8* bptr = Bp + (kg * 448 + wv * 112 + cg_);

    stageA(0, 0);
    __syncthreads();

    int buf = 0;
    for (int ks = 0; ks < NT; ++ks) {
        bf16x8 Bcur[7];
        const bf16x8* bk = bptr + (size_t)ks * 1792;
        #pragma unroll
        for (int c = 0; c < 7; ++c) Bcur[c] = bk[c * 16];
        if (ks < NT - 1) stageA(ks + 1, buf ^ 1);
        const bf16x8* As8 = (const bf16x8*)As4 + buf * 128;
        bf16x8 af[2];
        #pragma unroll
        for (int rt = 0; rt < 2; ++rt)
            af[rt] = As8[kg * 32 + rt * 16 + cg_];
        #pragma unroll
        for (int ct = 0; ct < 7; ++ct)
            #pragma unroll
            for (int rt = 0; rt < 2; ++rt)
                acc[rt][ct] = __builtin_amdgcn_mfma_f32_16x16x32_bf16(
                                  af[rt], Bcur[ct], acc[rt][ct], 0, 0, 0);
        __syncthreads();
        buf ^= 1;
    }

    float* redm = (float*)smem;
    float* reds = redm + 128;

    int colb = wv * 112;
    float bias[7];
    bool  cv[7];
    #pragma unroll
    for (int ct = 0; ct < 7; ++ct) {
        int c = colb + ct * 16 + cg_;
        cv[ct] = (c < DIM);
        bias[ct] = cv[ct] ? fcb[c] : 0.f;
    }
    #pragma unroll
    for (int rt = 0; rt < 2; ++rt)
        #pragma unroll
        for (int ct = 0; ct < 7; ++ct)
            acc[rt][ct] = acc[rt][ct] + bias[ct];

    f32x4 mx[2];
    #pragma unroll
    for (int rt = 0; rt < 2; ++rt) {
        f32x4 m = (f32x4){-1e30f, -1e30f, -1e30f, -1e30f};
        #pragma unroll
        for (int ct = 0; ct < 7; ++ct) {
            if (!cv[ct]) continue;
            #pragma unroll
            for (int j = 0; j < 4; ++j) m[j] = fmaxf(m[j], acc[rt][ct][j]);
        }
        #pragma unroll
        for (int msk = 1; msk < 16; msk <<= 1)
            #pragma unroll
            for (int j = 0; j < 4; ++j)
                m[j] = fmaxf(m[j], __shfl_xor(m[j], msk));
        mx[rt] = m;
    }
    __syncthreads();
    if (cg_ == 0) {
        #pragma unroll
        for (int rt = 0; rt < 2; ++rt)
            #pragma unroll
            for (int j = 0; j < 4; ++j)
                redm[(rt * 16 + kg * 4 + j) * 4 + wv] = mx[rt][j];
    }
    __syncthreads();
    f32x4 gm[2];
    #pragma unroll
    for (int rt = 0; rt < 2; ++rt)
        #pragma unroll
        for (int j = 0; j < 4; ++j) {
            int r = (rt * 16 + kg * 4 + j) * 4;
            gm[rt][j] = fmaxf(fmaxf(redm[r], redm[r + 1]),
                              fmaxf(redm[r + 2], redm[r + 3]));
        }

    f32x4 sm[2];
    #pragma unroll
    for (int rt = 0; rt < 2; ++rt) {
        f32x4 s = (f32x4){0.f, 0.f, 0.f, 0.f};
        #pragma unroll
        for (int ct = 0; ct < 7; ++ct) {
            if (!cv[ct]) continue;
            #pragma unroll
            for (int j = 0; j < 4; ++j)
                s[j] += __expf(acc[rt][ct][j] - gm[rt][j]);
        }
        #pragma unroll
        for (int msk = 1; msk < 16; msk <<= 1)
            #pragma unroll
            for (int j = 0; j < 4; ++j)
                s[j] += __shfl_xor(s[j], msk);
        sm[rt] = s;
    }
    if (cg_ == 0) {
        #pragma unroll
        for (int rt = 0; rt < 2; ++rt)
            #pragma unroll
            for (int j = 0; j < 4; ++j)
                reds[(rt * 16 + kg * 4 + j) * 4 + wv] = sm[rt][j];
    }
    __syncthreads();
    f32x4 lse[2];
    #pragma unroll
    for (int rt = 0; rt < 2; ++rt)
        #pragma unroll
        for (int j = 0; j < 4; ++j) {
            int r = (rt * 16 + kg * 4 + j) * 4;
            float t = reds[r] + reds[r + 1] + reds[r + 2] + reds[r + 3];
            lse[rt][j] = gm[rt][j] + __logf(t);
        }
    __syncthreads();

    #pragma unroll
    for (int rt = 0; rt < 2; ++rt) {
        #pragma unroll
        for (int ct = 0; ct < 7; ++ct) {
            int c = colb + ct * 16 + cg_;
            #pragma unroll
            for (int j = 0; j < 4; ++j)
                T[(kg * 4 + j) * TST + c] = acc[rt][ct][j];
        }
        if (wv == 0 && cg_ == 0) {
            #pragma unroll
            for (int j = 0; j < 4; ++j)
                lsebuf[kg * 4 + j] = lse[rt][j];
        }
        __syncthreads();
        #pragma unroll
        for (int q = 0; q < 7; ++q) {
            int idx = tid + q * 256;
            int row = idx / 112;
            int c4  = idx - row * 112;
            int grow2 = row0 + rt * 16 + row;
            if (grow2 < n && c4 <= 98) {
                float4 v = *reinterpret_cast<const float4*>(&T[row * TST + c4 * 4]);
                float L = lsebuf[row];
                size_t base = (size_t)grow2 * DIM + c4 * 4;
                if (c4 <= 97) {
                    *reinterpret_cast<float2*>(&z[base])        = make_float2(v.x, v.y);
                    *reinterpret_cast<float2*>(&z[base + 2])    = make_float2(v.z, v.w);
                    *reinterpret_cast<float2*>(&outp[base])     = make_float2(v.x - L, v.y - L);
                    *reinterpret_cast<float2*>(&outp[base + 2]) = make_float2(v.z - L, v.w - L);
                } else {
                    *reinterpret_cast<float2*>(&z[base])    = make_float2(v.x, v.y);
                    *reinterpret_cast<float2*>(&outp[base]) = make_float2(v.x - L, v.y - L);
                }
            }
        }
        __syncthreads();
    }
}

// ---------------------------------------------------------------------------
extern "C" void kernel_launch(void* const* d_in, const int* in_sizes, int n_in,
                              void* d_out, int out_size, void* d_ws, size_t ws_size,
                              hipStream_t stream) {
    int n = in_sizes[0] / 2;       // 50000 nodes
    int e = in_sizes[1] / 2;       // 800000 edges

    const float2* x2   = (const float2*)d_in[0];
    const int*   ei    = (const int*)d_in[1];
    const float* Wg    = (const float*)d_in[2];
    const float* bg    = (const float*)d_in[3];
    const float* gamma = (const float*)d_in[4];
    const float* beta  = (const float*)d_in[5];
    const float* mean  = (const float*)d_in[6];
    const float* var   = (const float*)d_in[7];
    const float* fcw   = (const float*)d_in[8];
    const float* fcb   = (const float*)d_in[9];

    float* out = (float*)d_out;
    float* z   = out + (size_t)n * DIM;

    char* wsb = (char*)d_ws;
    unsigned* degc  = (unsigned*)wsb;
    float*    yover = (float*)(degc + n);
    unsigned* ocnt  = (unsigned*)(yover + 2 * (size_t)n);
    float2*   xs2   = (float2*)(ocnt + 4);
    uint2*    olist = (uint2*)(xs2 + n);
    size_t off = (size_t)(5 * n + 4) * 4 + (size_t)e * 8;
    off = (off + 255) & ~(size_t)255;
    unsigned* payload = (unsigned*)(wsb + off);
    off += (size_t)n * MAXD * 4;
    off = (off + 255) & ~(size_t)255;
    bf16x8* Bp = (bf16x8*)(wsb + off);
    off += (size_t)NT * 4 * NP * 16;
    float4* Pk = (float4*)(wsb + off);
    off += (size_t)KP * 16;
    float* Ok  = (float*)(wsb + off);

    int zwords = 3 * n + 4;
    int z4 = (zwords + 3) / 4;
    int zb = (z4 + 255) / 256;
    int prep_blocks = zb + 2 + (NT * 4 * NP + 255) / 256;
    int eb16 = (e / 16 + 255) / 256 + 1;
    int nb0 = (n + 255) / 256;

    prep_kernel<<<prep_blocks, 256, 0, stream>>>(Wg, bg, gamma, beta, mean, var,
                                                 fcw, (uint4*)degc, Pk, Ok, Bp,
                                                 z4, zb);
    place_kernel<<<eb16, 256, 0, stream>>>(ei, degc, payload, ocnt, olist, e);
    xs_cleanup_kernel<<<nb0 + 2, 256, 0, stream>>>(x2, degc, xs2, olist, ocnt,
                                                   yover, n, nb0);

    int gm = (n + 31) / 32;
    gemm_fused<<<gm, 256, 0, stream>>>(xs2, degc, payload, yover,
                                       Pk, Ok, Bp, fcb, out, z, n);
}